// Round 7
// baseline (1181.299 us; speedup 1.0000x reference)
//
#include <hip/hip_runtime.h>
#include <math.h>

#define BB 8
#define NN 2048
#define PP 64
#define KK 32
#define DD 384
#define DEPTH 12
#define DI 768
#define DS 16
#define DCONV 4
#define DTR 24
#define NC 40
#define LL 128  // 2*PP
#define XROW (DTR + 2 * DS)  // 56
#define NR (BB * LL)         // 1024
#define XZSPLIT 24           // split-K for xdbl mfma gemm (kchunk = 32)
#define OSPLIT 4             // split-K for out-proj gemm

using bf16x8 = __attribute__((ext_vector_type(8))) short;
using floatx4 = __attribute__((ext_vector_type(4))) float;

// ---------------------------------------------------------------- helpers
__device__ __forceinline__ float gelu_exact(float x) {
    return 0.5f * x * (1.0f + erff(x * 0.70710678118654752440f));
}
__device__ __forceinline__ float siluf(float x) {
    return x / (1.0f + expf(-x));
}
__device__ __forceinline__ unsigned short f2bf(float f) {
    unsigned u = __float_as_uint(f);
    u += 0x7fffu + ((u >> 16) & 1u);   // round-to-nearest-even
    return (unsigned short)(u >> 16);
}
__device__ __forceinline__ unsigned spread_bits(unsigned v) {
    v &= 1023u;
    v = (v | (v << 16)) & 50331903u;
    v = (v | (v << 8)) & 50393103u;
    v = (v | (v << 4)) & 51130563u;
    v = (v | (v << 2)) & 153391689u;
    return v;
}

// ---------------------------------------------------------------- fp32 -> bf16 bulk convert
__global__ void k_w2bf(const float* __restrict__ src, unsigned short* __restrict__ dst, int n)
{
    int i = (blockIdx.x * 256 + threadIdx.x) * 4;
    if (i >= n) return;
    float4 v = *(const float4*)(src + i);
    dst[i + 0] = f2bf(v.x);
    dst[i + 1] = f2bf(v.y);
    dst[i + 2] = f2bf(v.z);
    dst[i + 3] = f2bf(v.w);
}

// ---------------------------------------------------------------- xp -> padded bf16 (64 rows, rows 56..63 zero)
__global__ void k_xp2bf(const float* __restrict__ xp, unsigned short* __restrict__ dst)
{
    int idx = blockIdx.x * 256 + threadIdx.x;
    if (idx >= DEPTH * 64 * DI) return;
    int i = idx / (64 * DI);
    int rem = idx - i * 64 * DI;
    int n = rem / DI, k = rem % DI;
    float v = (n < XROW) ? xp[(size_t)i * XROW * DI + (size_t)n * DI + k] : 0.f;
    dst[idx] = f2bf(v);
}

// ---------------------------------------------------------------- KNN: one block per (b,p)
__global__ __launch_bounds__(256) void k_knn(const float* __restrict__ data,
                                             int* __restrict__ knn_out,
                                             float* __restrict__ centers)
{
    const int bp = blockIdx.x;
    const int b = bp >> 6, p = bp & 63;
    const int tid = threadIdx.x;
    const int lane = tid & 63, wid = tid >> 6;
    const float* X = data + (size_t)b * NN * 3;

    const float cx = X[p * 32 * 3 + 0];
    const float cy = X[p * 32 * 3 + 1];
    const float cz = X[p * 32 * 3 + 2];
    if (tid == 0) {
        centers[(b * PP + p) * 3 + 0] = cx;
        centers[(b * PP + p) * 3 + 1] = cy;
        centers[(b * PP + p) * 3 + 2] = cz;
    }

    unsigned long long pk[8];
#pragma unroll
    for (int q = 0; q < 8; q++) {
        int i = tid + 256 * q;
        float dx = cx - X[i * 3 + 0];
        float dy = cy - X[i * 3 + 1];
        float dz = cz - X[i * 3 + 2];
        float d2 = dx * dx + dy * dy + dz * dz;
        pk[q] = ((unsigned long long)__float_as_uint(d2) << 32) | (unsigned)i;
    }

    __shared__ unsigned long long wred[4];
    __shared__ int klist[KK];
    for (int k = 0; k < KK; k++) {
        unsigned long long m = pk[0];
#pragma unroll
        for (int q = 1; q < 8; q++) m = pk[q] < m ? pk[q] : m;
#pragma unroll
        for (int off = 32; off; off >>= 1) {
            unsigned long long o = __shfl_xor(m, off);
            m = o < m ? o : m;
        }
        if (lane == 0) wred[wid] = m;
        __syncthreads();
        unsigned long long g = wred[0];
#pragma unroll
        for (int w = 1; w < 4; w++) g = wred[w] < g ? wred[w] : g;
#pragma unroll
        for (int q = 0; q < 8; q++)
            if (pk[q] == g) pk[q] = ~0ull;
        if (tid == 0) klist[k] = (int)(g & 0xffffffffu);
        __syncthreads();
    }
    if (tid < KK) knn_out[bp * KK + tid] = klist[tid];
}

// ---------------------------------------------------------------- patch-embed MLP: one block per (b,p)
// layers 1-2 fp32 (small), layer 3 (32x384x128, 80% of FLOPs) via bf16 MFMA.
__global__ __launch_bounds__(256) void k_pe_mlp(
    const float* __restrict__ data, const int* __restrict__ knn_in,
    const float* __restrict__ w1, const float* __restrict__ b1,
    const float* __restrict__ g1, const float* __restrict__ be1,
    const float* __restrict__ w2, const float* __restrict__ b2,
    const float* __restrict__ g2, const float* __restrict__ be2,
    const unsigned short* __restrict__ w3bf, const float* __restrict__ b3,
    const float* __restrict__ g3, const float* __restrict__ be3,
    float* __restrict__ tokens)
{
    const int bp = blockIdx.x;
    const int b = bp >> 6, p = bp & 63;
    const int tid = threadIdx.x;
    const float* X = data + (size_t)b * NN * 3;
    const float inv_den = 0.99999500003749968752f; // 1/sqrt(1+1e-5)

    __shared__ float nxs[KK * 3];
    __shared__ float h1s[KK * 64];
    __shared__ short h2b[KK * 136];   // bf16, row stride 136 (272B): frag reads 2-way (free)

    const float cx = X[p * 32 * 3 + 0];
    const float cy = X[p * 32 * 3 + 1];
    const float cz = X[p * 32 * 3 + 2];
    if (tid < KK) {
        int q = knn_in[bp * KK + tid];
        nxs[tid * 3 + 0] = X[q * 3 + 0] - cx;
        nxs[tid * 3 + 1] = X[q * 3 + 1] - cy;
        nxs[tid * 3 + 2] = X[q * 3 + 2] - cz;
    }
    __syncthreads();

    for (int e = tid; e < KK * 64; e += 256) {
        int j = e >> 6, c = e & 63;
        float v = nxs[j * 3 + 0] * w1[c * 3 + 0] + nxs[j * 3 + 1] * w1[c * 3 + 1] +
                  nxs[j * 3 + 2] * w1[c * 3 + 2] + b1[c];
        v = v * (g1[c] * inv_den) + be1[c];
        h1s[j * 64 + c] = gelu_exact(v);
    }
    __syncthreads();

    for (int e = tid; e < KK * 128; e += 256) {
        int j = e >> 7, c = e & 127;
        const float4* wr = (const float4*)(w2 + (size_t)c * 64);
        const float4* hr = (const float4*)(h1s + j * 64);
        float acc = 0.f;
#pragma unroll
        for (int q = 0; q < 16; q++) {
            float4 wv = wr[q], hv = hr[q];
            acc += hv.x * wv.x + hv.y * wv.y + hv.z * wv.z + hv.w * wv.w;
        }
        float v = (acc + b2[c]) * (g2[c] * inv_den) + be2[c];
        h2b[j * 136 + c] = (short)f2bf(gelu_exact(v));
    }
    __syncthreads();

    // ---- layer 3: MFMA. A = h2b (32x128), B = w3bf (384x128); wave wn covers 96 cols.
    const int wave = tid >> 6, lane = tid & 63;
    const int quad = lane >> 4, r = lane & 15;
    floatx4 acc3[2][6] = {};
#pragma unroll
    for (int ks = 0; ks < 4; ks++) {
        const int k0 = ks * 32;
        bf16x8 af[2];
        af[0] = *(const bf16x8*)(h2b + (size_t)r * 136 + quad * 8 + k0);
        af[1] = *(const bf16x8*)(h2b + (size_t)(16 + r) * 136 + quad * 8 + k0);
        bf16x8 bfv[6];
#pragma unroll
        for (int nj = 0; nj < 6; nj++) {
            int n = wave * 96 + nj * 16 + r;
            bfv[nj] = *(const bf16x8*)(w3bf + (size_t)n * 128 + quad * 8 + k0);
        }
#pragma unroll
        for (int mi = 0; mi < 2; mi++)
#pragma unroll
            for (int nj = 0; nj < 6; nj++)
                acc3[mi][nj] = __builtin_amdgcn_mfma_f32_16x16x32_bf16(af[mi], bfv[nj], acc3[mi][nj], 0, 0, 0);
    }
    // epilogue: BN affine BEFORE max (scale may be negative), then max over 32 rows.
#pragma unroll
    for (int nj = 0; nj < 6; nj++) {
        int col = wave * 96 + nj * 16 + r;
        float sc = g3[col] * inv_den;
        float offc = b3[col] * sc + be3[col];
        float m = -3.4e38f;
#pragma unroll
        for (int mi = 0; mi < 2; mi++)
#pragma unroll
            for (int r2 = 0; r2 < 4; r2++)
                m = fmaxf(m, acc3[mi][nj][r2] * sc + offc);
        m = fmaxf(m, __shfl_xor(m, 16));
        m = fmaxf(m, __shfl_xor(m, 32));
        if (quad == 0) tokens[(size_t)bp * DD + col] = m;
    }
}

// ---------------------------------------------------------------- SFC orders
__global__ __launch_bounds__(64) void k_sfc(const float* __restrict__ centers,
                                            int* __restrict__ order_h,
                                            int* __restrict__ order_th)
{
    const int b = blockIdx.x;
    const int tid = threadIdx.x;
    float cc[3];
    cc[0] = centers[(b * PP + tid) * 3 + 0];
    cc[1] = centers[(b * PP + tid) * 3 + 1];
    cc[2] = centers[(b * PP + tid) * 3 + 2];

    __shared__ float csh[PP][3];
    __shared__ float slo[3], shi[3];
    csh[tid][0] = cc[0]; csh[tid][1] = cc[1]; csh[tid][2] = cc[2];
    __syncthreads();
    if (tid == 0) {
        for (int k = 0; k < 3; k++) {
            float lo = csh[0][k], hi = csh[0][k];
            for (int j = 1; j < PP; j++) { lo = fminf(lo, csh[j][k]); hi = fmaxf(hi, csh[j][k]); }
            slo[k] = lo; shi[k] = hi;
        }
    }
    __syncthreads();

    int q[3];
    for (int k = 0; k < 3; k++) {
        float t = (cc[k] - slo[k]) / (shi[k] - slo[k] + 1e-6f) * 1023.0f;
        int qi = (int)t;
        qi = qi < 0 ? 0 : (qi > 1023 ? 1023 : qi);
        q[k] = qi;
    }
    unsigned kh = spread_bits((unsigned)q[0]) | (spread_bits((unsigned)q[1]) << 1) |
                  (spread_bits((unsigned)q[2]) << 2);
    unsigned kt = spread_bits((unsigned)q[2]) | (spread_bits((unsigned)q[1]) << 1) |
                  (spread_bits((unsigned)q[0]) << 2);

    __shared__ unsigned khs[PP], kts[PP];
    khs[tid] = kh; kts[tid] = kt;
    __syncthreads();
    int rh = 0, rt = 0;
    for (int j = 0; j < PP; j++) {
        unsigned a = khs[j];
        rh += (a < kh) || (a == kh && j < tid);
        unsigned c = kts[j];
        rt += (c < kt) || (c == kt && j < tid);
    }
    order_h[b * PP + rh] = tid;
    order_th[b * PP + rt] = tid;
}

// ---------------------------------------------------------------- build token sequence
__global__ void k_build_t(const float* __restrict__ tokens,
                          const int* __restrict__ order_h, const int* __restrict__ order_th,
                          const float* __restrict__ hs, const float* __restrict__ hb,
                          const float* __restrict__ ts, const float* __restrict__ tb,
                          const float* __restrict__ pos, float* __restrict__ t)
{
    int idx = blockIdx.x * blockDim.x + threadIdx.x;
    if (idx >= BB * LL * DD) return;
    int d = idx % DD;
    int l = (idx / DD) % LL;
    int b = idx / (DD * LL);
    float v;
    if (l < PP) {
        int src = order_h[b * PP + l];
        v = tokens[((size_t)b * PP + src) * DD + d] * hs[d] + hb[d] + pos[l * DD + d];
    } else {
        int ll2 = l - PP;
        int src = order_th[b * PP + ll2];
        v = tokens[((size_t)b * PP + src) * DD + d] * ts[d] + tb[d] + pos[ll2 * DD + d];
    }
    t[idx] = v;
}

// ---------------------------------------------------------------- residual-accumulate + LN stats + bf16 LN output
__global__ __launch_bounds__(256) void k_stats(float* __restrict__ t,
                                               const float* __restrict__ parts,
                                               const float* __restrict__ g,
                                               const float* __restrict__ gb,
                                               unsigned short* __restrict__ tbf)
{
    const int tid = threadIdx.x;
    const int wid = tid >> 6, lane = tid & 63;
    const int row = blockIdx.x * 4 + wid;
    const size_t base = (size_t)row * DD;
    float v[6];
    float s = 0.f;
#pragma unroll
    for (int j = 0; j < 6; j++) {
        int i = lane + 64 * j;
        float x = t[base + i];
        if (parts) {
            x += parts[base + i] + parts[(size_t)NR * DD + base + i] +
                 parts[2 * (size_t)NR * DD + base + i] + parts[3 * (size_t)NR * DD + base + i];
            t[base + i] = x;
        }
        v[j] = x; s += x;
    }
#pragma unroll
    for (int off = 32; off; off >>= 1) s += __shfl_xor(s, off);
    float mean = s * (1.0f / DD);
    float vs = 0.f;
#pragma unroll
    for (int j = 0; j < 6; j++) { float dd = v[j] - mean; vs += dd * dd; }
#pragma unroll
    for (int off = 32; off; off >>= 1) vs += __shfl_xor(vs, off);
    float inv = 1.0f / sqrtf(vs * (1.0f / DD) + 1e-5f);
#pragma unroll
    for (int j = 0; j < 6; j++) {
        int i = lane + 64 * j;
        tbf[base + i] = f2bf((v[j] - mean) * inv * g[i] + gb[i]);
    }
}

// ---------------------------------------------------------------- bf16 MFMA GEMM, 128x128 tile, 4 waves
__global__ __launch_bounds__(256) void k_mfma_gemm(
    const unsigned short* __restrict__ Abf, int lda,
    const unsigned short* __restrict__ Wbf, int ldb,
    float* __restrict__ C, int ldc, size_t cstride, int kchunk)
{
    const int tid = threadIdx.x;
    const int wave = tid >> 6, lane = tid & 63;
    const int quad = lane >> 4, r = lane & 15;
    const int wm = wave >> 1, wn = wave & 1;
    const int m0 = blockIdx.y * 128 + wm * 64;
    const int n0 = blockIdx.x * 128 + wn * 64;
    const int kbeg = blockIdx.z * kchunk;
    float* Cz = C + (size_t)blockIdx.z * cstride;

    floatx4 acc[4][4] = {};

    const unsigned short* Ab = Abf + (size_t)(m0 + r) * lda + quad * 8 + kbeg;
    const unsigned short* Bb = Wbf + (size_t)(n0 + r) * ldb + quad * 8 + kbeg;

    for (int k0 = 0; k0 < kchunk; k0 += 32) {
        bf16x8 af[4], bf[4];
#pragma unroll
        for (int i = 0; i < 4; i++) {
            af[i] = *(const bf16x8*)(Ab + (size_t)(i * 16) * lda + k0);
            bf[i] = *(const bf16x8*)(Bb + (size_t)(i * 16) * ldb + k0);
        }
#pragma unroll
        for (int i = 0; i < 4; i++)
#pragma unroll
            for (int j = 0; j < 4; j++)
                acc[i][j] = __builtin_amdgcn_mfma_f32_16x16x32_bf16(af[i], bf[j], acc[i][j], 0, 0, 0);
    }

    // C/D layout: col = lane&15, row = quad*4 + reg
#pragma unroll
    for (int i = 0; i < 4; i++)
#pragma unroll
        for (int r2 = 0; r2 < 4; r2++) {
            float* cp = Cz + (size_t)(m0 + i * 16 + quad * 4 + r2) * ldc + n0 + r;
#pragma unroll
            for (int j = 0; j < 4; j++)
                cp[j * 16] = acc[i][j][r2];
        }
}

// ---------------------------------------------------------------- xdbl MFMA GEMM, conv+SiLU fused into A-fragment load
// parts[z][NR][XROW] = silu(conv(xz))[:, z*32 .. z*32+31] @ xp^T.  Each (row,ch)
// computed exactly once (split-K splits channels).  Block: 256 thr, M=256, N=64, K=32.
__global__ __launch_bounds__(256) void k_mfma_xdbl(
    const float* __restrict__ xz, const float* __restrict__ cw, const float* __restrict__ cb,
    const unsigned short* __restrict__ xpbf,  // 64 x DI bf16 (rows 56..63 zero)
    float* __restrict__ parts)
{
    const int tid = threadIdx.x;
    const int wave = tid >> 6, lane = tid & 63;
    const int quad = lane >> 4, r = lane & 15;
    const int rowbase = blockIdx.y * 256 + wave * 64;
    const int z = blockIdx.z;
    const int ch0 = z * (DI / XZSPLIT) + quad * 8;

    float cwr[8][4], cbr[8];
#pragma unroll
    for (int q = 0; q < 8; q++) {
        *(float4*)cwr[q] = *(const float4*)(cw + (size_t)(ch0 + q) * 4);
        cbr[q] = cb[ch0 + q];
    }

    bf16x8 bfv[4];
#pragma unroll
    for (int nj = 0; nj < 4; nj++)
        bfv[nj] = *(const bf16x8*)(xpbf + (size_t)(nj * 16 + r) * DI + ch0);

    floatx4 acc[4][4] = {};
#pragma unroll
    for (int mi = 0; mi < 4; mi++) {
        const int m = rowbase + mi * 16 + r;
        const int l = m & (LL - 1);
        const float* xzr = xz + (size_t)m * (2 * DI) + ch0;
        float u[8];
#pragma unroll
        for (int q = 0; q < 8; q++) u[q] = cbr[q];
#pragma unroll
        for (int j = 0; j < DCONV; j++) {
            int lt = l - (DCONV - 1) + j;
            if (lt >= 0) {
                const float* xr = xzr + (ptrdiff_t)(lt - l) * (2 * DI);
                float4 x0 = *(const float4*)(xr);
                float4 x1 = *(const float4*)(xr + 4);
                u[0] += x0.x * cwr[0][j]; u[1] += x0.y * cwr[1][j];
                u[2] += x0.z * cwr[2][j]; u[3] += x0.w * cwr[3][j];
                u[4] += x1.x * cwr[4][j]; u[5] += x1.y * cwr[5][j];
                u[6] += x1.z * cwr[6][j]; u[7] += x1.w * cwr[7][j];
            }
        }
        bf16x8 af;
#pragma unroll
        for (int q = 0; q < 8; q++) af[q] = (short)f2bf(siluf(u[q]));
#pragma unroll
        for (int nj = 0; nj < 4; nj++)
            acc[mi][nj] = __builtin_amdgcn_mfma_f32_16x16x32_bf16(af, bfv[nj], acc[mi][nj], 0, 0, 0);
    }

    float* out = parts + (size_t)z * NR * XROW;
#pragma unroll
    for (int mi = 0; mi < 4; mi++)
#pragma unroll
        for (int nj = 0; nj < 4; nj++) {
            int col = nj * 16 + r;
            if (col < XROW) {
#pragma unroll
                for (int r2 = 0; r2 < 4; r2++) {
                    int row = rowbase + mi * 16 + quad * 4 + r2;
                    out[(size_t)row * XROW + col] = acc[mi][nj][r2];
                }
            }
        }
}

// ---------------------------------------------------------------- reduce xdbl partials
__global__ void k_xred(const float* __restrict__ parts, float* __restrict__ xdbl)
{
    int i = blockIdx.x * 256 + threadIdx.x;
    if (i >= NR * XROW) return;
    float s = 0.f;
#pragma unroll
    for (int z = 0; z < XZSPLIT; z++) s += parts[(size_t)z * NR * XROW + i];
    xdbl[i] = s;
}

// ---------------------------------------------------------------- chunk-parallel selective scan (y out in bf16)
__global__ __launch_bounds__(256) void k_scan(
    const float* __restrict__ xdbl, const float* __restrict__ xz,
    const float* __restrict__ cw, const float* __restrict__ cb,
    const float* __restrict__ dtw, const float* __restrict__ dtb,
    const float* __restrict__ Alog, const float* __restrict__ Dp,
    unsigned short* __restrict__ ybf)
{
    const int tid = threadIdx.x;
    const int b = blockIdx.x / (DI / 2);
    const int d0 = (blockIdx.x % (DI / 2)) * 2;

    __shared__ float da[LL][33];
    __shared__ float Bsh[LL][DS];
    __shared__ float Csh[LL][DS];
    __shared__ float dus[LL][2];
    __shared__ float us[LL][2];
    __shared__ float zs[LL][2];
    __shared__ float ApL[2][DS][9];
    __shared__ float HlL[2][DS][9];
    __shared__ float hst[2][DS][9];

    {
        const int t = tid >> 1, dl = tid & 1;
        const int d = d0 + dl;
        const size_t row = (size_t)b * LL + t;
        const float* xd = xdbl + row * XROW;
        const float* w = dtw + d * DTR;
        float acc = dtb[d];
#pragma unroll
        for (int k = 0; k < DTR; k++) acc += xd[k] * w[k];
        float delta = fmaxf(acc, 0.f) + log1pf(__expf(-fabsf(acc)));  // softplus
        float u = cb[d];
#pragma unroll
        for (int j = 0; j < DCONV; j++) {
            int lt = t - (DCONV - 1) + j;
            if (lt >= 0) u += xz[((size_t)b * LL + lt) * (2 * DI) + d] * cw[d * DCONV + j];
        }
        u = siluf(u);
        dus[t][dl] = delta * u;
        us[t][dl] = u;
        zs[t][dl] = siluf(xz[row * (2 * DI) + DI + d]);
#pragma unroll
        for (int s = 0; s < DS; s++)
            da[t][2 * s + dl] = __expf(delta * (-__expf(Alog[d * DS + s])));
    }
    for (int i = tid; i < LL * DS; i += 256) {
        int t = i >> 4, s = i & 15;
        const float* xd = xdbl + ((size_t)b * LL + t) * XROW;
        Bsh[t][s] = xd[DTR + s];
        Csh[t][s] = xd[DTR + DS + s];
    }
    __syncthreads();

    const int s = tid & 15;
    const int dl = (tid >> 4) & 1;
    const int c = tid >> 5;

    {
        float h = 0.f, Ap = 1.f;
#pragma unroll
        for (int q = 0; q < 16; q++) {
            int t = c * 16 + q;
            float a = da[t][2 * s + dl];
            h = h * a + dus[t][dl] * Bsh[t][s];
            Ap *= a;
        }
        ApL[dl][s][c] = Ap;
        HlL[dl][s][c] = h;
    }
    __syncthreads();
    if (tid < 32) {
        int s2 = tid & 15, d2 = tid >> 4;
        float hs = 0.f;
#pragma unroll
        for (int cc = 0; cc < 8; cc++) {
            hst[d2][s2][cc] = hs;
            hs = ApL[d2][s2][cc] * hs + HlL[d2][s2][cc];
        }
    }
    __syncthreads();

    {
        const float Dd = Dp[d0 + dl];
        float h = hst[dl][s][c];
        unsigned short* yc = ybf + ((size_t)b * LL + c * 16) * DI + (d0 + dl);
#pragma unroll
        for (int q = 0; q < 16; q++) {
            int t = c * 16 + q;
            float a = da[t][2 * s + dl];
            h = h * a + dus[t][dl] * Bsh[t][s];
            float p = h * Csh[t][s];
            p += __shfl_xor(p, 1, 16);
            p += __shfl_xor(p, 2, 16);
            p += __shfl_xor(p, 4, 16);
            p += __shfl_xor(p, 8, 16);
            if (s == 0) yc[(size_t)q * DI] = f2bf((p + Dd * us[t][dl]) * zs[t][dl]);
        }
    }
}

// ---------------------------------------------------------------- final layernorm (wave per row) + residual partials
__global__ __launch_bounds__(64) void k_ln(const float* __restrict__ x,
                                           const float* __restrict__ parts,
                                           const float* __restrict__ g,
                                           const float* __restrict__ bb,
                                           float* __restrict__ y)
{
    const int row = blockIdx.x;
    const int tid = threadIdx.x;
    const size_t base = (size_t)row * DD;
    float v[6];
    float s = 0.f;
#pragma unroll
    for (int j = 0; j < 6; j++) {
        int i = tid + 64 * j;
        float xv = x[base + i] + parts[base + i] + parts[(size_t)NR * DD + base + i] +
                   parts[2 * (size_t)NR * DD + base + i] + parts[3 * (size_t)NR * DD + base + i];
        v[j] = xv; s += xv;
    }
#pragma unroll
    for (int off = 32; off; off >>= 1) s += __shfl_xor(s, off);
    float mean = s * (1.0f / DD);
    float vs = 0.f;
#pragma unroll
    for (int j = 0; j < 6; j++) { float dd = v[j] - mean; vs += dd * dd; }
#pragma unroll
    for (int off = 32; off; off >>= 1) vs += __shfl_xor(vs, off);
    float inv = 1.0f / sqrtf(vs * (1.0f / DD) + 1e-5f);
#pragma unroll
    for (int j = 0; j < 6; j++) {
        int i = tid + 64 * j;
        y[base + i] = (v[j] - mean) * inv * g[i] + bb[i];
    }
}

// ---------------------------------------------------------------- mean over L
__global__ void k_mean(const float* __restrict__ xln, float* __restrict__ pooled)
{
    int idx = blockIdx.x * blockDim.x + threadIdx.x;
    if (idx >= BB * DD) return;
    int b = idx / DD, d = idx % DD;
    float sv = 0.f;
    for (int l = 0; l < LL; l++) sv += xln[((size_t)b * LL + l) * DD + d];
    pooled[idx] = sv / (float)LL;
}

// ---------------------------------------------------------------- head MLP (one block per batch)
__global__ __launch_bounds__(256) void k_mlp(const float* __restrict__ pooled,
    const float* __restrict__ w1, const float* __restrict__ b1,
    const float* __restrict__ w2, const float* __restrict__ b2,
    const float* __restrict__ w3, const float* __restrict__ b3,
    float* __restrict__ out)
{
    int b = blockIdx.x, tid = threadIdx.x;
    __shared__ float pl[DD];
    __shared__ float h1[256];
    __shared__ float h2[64];
    for (int i = tid; i < DD; i += 256) pl[i] = pooled[b * DD + i];
    __syncthreads();
    {
        float acc = b1[tid];
        const float* wr = w1 + (size_t)tid * DD;
        for (int k = 0; k < DD; k++) acc += pl[k] * wr[k];
        h1[tid] = fmaxf(acc, 0.f);
    }
    __syncthreads();
    if (tid < 64) {
        float acc = b2[tid];
        const float* wr = w2 + (size_t)tid * 256;
        for (int k = 0; k < 256; k++) acc += h1[k] * wr[k];
        h2[tid] = fmaxf(acc, 0.f);
    }
    __syncthreads();
    if (tid < NC) {
        float acc = b3[tid];
        const float* wr = w3 + (size_t)tid * 64;
        for (int k = 0; k < 64; k++) acc += h2[k] * wr[k];
        out[b * NC + tid] = acc;
    }
}

// ---------------------------------------------------------------- launch
extern "C" void kernel_launch(void* const* d_in, const int* in_sizes, int n_in,
                              void* d_out, int out_size, void* d_ws, size_t ws_size,
                              hipStream_t stream)
{
    const float* data      = (const float*)d_in[0];
    const float* pe_w1     = (const float*)d_in[1];
    const float* pe_b1     = (const float*)d_in[2];
    const float* pe_g1     = (const float*)d_in[3];
    const float* pe_be1    = (const float*)d_in[4];
    const float* pe_w2     = (const float*)d_in[5];
    const float* pe_b2     = (const float*)d_in[6];
    const float* pe_g2     = (const float*)d_in[7];
    const float* pe_be2    = (const float*)d_in[8];
    const float* pe_w3     = (const float*)d_in[9];
    const float* pe_b3     = (const float*)d_in[10];
    const float* pe_g3     = (const float*)d_in[11];
    const float* pe_be3    = (const float*)d_in[12];
    const float* oi_h_scale  = (const float*)d_in[13];
    const float* oi_h_shift  = (const float*)d_in[14];
    const float* oi_th_scale = (const float*)d_in[15];
    const float* oi_th_shift = (const float*)d_in[16];
    const float* pos_embed = (const float*)d_in[17];
    const float* blk_ln_g  = (const float*)d_in[18];
    const float* blk_ln_b  = (const float*)d_in[19];
    const float* blk_in_w  = (const float*)d_in[20];
    const float* blk_conv_w = (const float*)d_in[21];
    const float* blk_conv_b = (const float*)d_in[22];
    const float* blk_xp_w  = (const float*)d_in[23];
    const float* blk_dt_w  = (const float*)d_in[24];
    const float* blk_dt_b  = (const float*)d_in[25];
    const float* blk_Alog  = (const float*)d_in[26];
    const float* blk_D     = (const float*)d_in[27];
    const float* blk_out_w = (const float*)d_in[28];
    const float* norm_g    = (const float*)d_in[29];
    const float* norm_b    = (const float*)d_in[30];
    const float* mlp_w1    = (const float*)d_in[31];
    const float* mlp_b1    = (const float*)d_in[32];
    const float* mlp_w2    = (const float*)d_in[33];
    const float* mlp_b2    = (const float*)d_in[34];
    const float* mlp_w3    = (const float*)d_in[35];
    const float* mlp_b3    = (const float*)d_in[36];

    float* ws = (float*)d_ws;
    size_t off = 0;
    auto alloc = [&](size_t n) { float* p = ws + off; off += (n + 63) & ~(size_t)63; return p; };
    float* tokens  = alloc((size_t)BB * PP * DD);
    float* centers = alloc((size_t)BB * PP * 3);
    int*   order_h = (int*)alloc((size_t)BB * PP);
    int*   order_th= (int*)alloc((size_t)BB * PP);
    int*   knn_idx = (int*)alloc((size_t)BB * PP * KK);
    float* t    = alloc((size_t)NR * DD);
    float* xln  = alloc((size_t)NR * DD);
    float* xz   = alloc((size_t)NR * 2 * DI);
    float* xdbl = alloc((size_t)NR * XROW);
    float* pooled = alloc((size_t)BB * DD);
    float* parts_out = alloc((size_t)OSPLIT * NR * DD);
    float* parts_x   = alloc((size_t)XZSPLIT * NR * XROW);
    unsigned short* tbf   = (unsigned short*)alloc((size_t)NR * DD / 2);
    unsigned short* ybf   = (unsigned short*)alloc((size_t)NR * DI / 2);
    unsigned short* inwbf = (unsigned short*)alloc((size_t)DEPTH * 2 * DI * DD / 2);
    unsigned short* owbf  = (unsigned short*)alloc((size_t)DEPTH * DD * DI / 2);
    unsigned short* xpbf  = (unsigned short*)alloc((size_t)DEPTH * 64 * DI / 2);
    unsigned short* w3bf  = (unsigned short*)alloc((size_t)DD * 128 / 2);

    // one-shot weight conversion to bf16
    {
        int n1 = DEPTH * 2 * DI * DD;
        int n2 = DEPTH * DD * DI;
        int n3 = DD * 128;
        int n4 = DEPTH * 64 * DI;
        k_w2bf<<<(n1 / 4 + 255) / 256, 256, 0, stream>>>(blk_in_w, inwbf, n1);
        k_w2bf<<<(n2 / 4 + 255) / 256, 256, 0, stream>>>(blk_out_w, owbf, n2);
        k_w2bf<<<(n3 / 4 + 255) / 256, 256, 0, stream>>>(pe_w3, w3bf, n3);
        k_xp2bf<<<(n4 + 255) / 256, 256, 0, stream>>>(blk_xp_w, xpbf);
    }

    k_knn<<<BB * PP, 256, 0, stream>>>(data, knn_idx, centers);
    k_pe_mlp<<<BB * PP, 256, 0, stream>>>(data, knn_idx,
        pe_w1, pe_b1, pe_g1, pe_be1, pe_w2, pe_b2, pe_g2, pe_be2,
        w3bf, pe_b3, pe_g3, pe_be3, tokens);
    k_sfc<<<BB, 64, 0, stream>>>(centers, order_h, order_th);
    {
        int nt = BB * LL * DD;
        k_build_t<<<(nt + 255) / 256, 256, 0, stream>>>(tokens, order_h, order_th,
            oi_h_scale, oi_h_shift, oi_th_scale, oi_th_shift, pos_embed, t);
    }

    for (int i = 0; i < DEPTH; i++) {
        const float* ln_g = blk_ln_g + i * DD;
        const float* ln_b = blk_ln_b + i * DD;
        const float* cw   = blk_conv_w + (size_t)i * DI * DCONV;
        const float* cb   = blk_conv_b + (size_t)i * DI;
        const float* dtw  = blk_dt_w + (size_t)i * DI * DTR;
        const float* dtb  = blk_dt_b + (size_t)i * DI;
        const float* Al   = blk_Alog + (size_t)i * DI * DS;
        const float* Dpp  = blk_D + (size_t)i * DI;
        const unsigned short* inw = inwbf + (size_t)i * 2 * DI * DD;
        const unsigned short* ow  = owbf + (size_t)i * DD * DI;
        const unsigned short* xpb = xpbf + (size_t)i * 64 * DI;

        k_stats<<<NR / 4, 256, 0, stream>>>(t, (i == 0) ? nullptr : parts_out, ln_g, ln_b, tbf);
        k_mfma_gemm<<<dim3(2 * DI / 128, NR / 128, 1), 256, 0, stream>>>(
            tbf, DD, inw, DD, xz, 2 * DI, 0, DD);
        k_mfma_xdbl<<<dim3(1, NR / 256, XZSPLIT), 256, 0, stream>>>(
            xz, cw, cb, xpb, parts_x);
        k_xred<<<(NR * XROW + 255) / 256, 256, 0, stream>>>(parts_x, xdbl);
        k_scan<<<BB * DI / 2, 256, 0, stream>>>(xdbl, xz, cw, cb, dtw, dtb, Al, Dpp, ybf);
        k_mfma_gemm<<<dim3(DD / 128, NR / 128, OSPLIT), 256, 0, stream>>>(
            ybf, DI, ow, DI, parts_out, DD, (size_t)NR * DD, DI / OSPLIT);
    }

    k_ln<<<NR, 64, 0, stream>>>(t, parts_out, norm_g, norm_b, xln);
    k_mean<<<(BB * DD + 255) / 256, 256, 0, stream>>>(xln, pooled);
    k_mlp<<<BB, 256, 0, stream>>>(pooled, mlp_w1, mlp_b1, mlp_w2, mlp_b2, mlp_w3, mlp_b3,
                                  (float*)d_out);
}

// Round 8
// 1142.955 us; speedup vs baseline: 1.0335x; 1.0335x over previous
//
#include <hip/hip_runtime.h>
#include <math.h>

#define BB 8
#define NN 2048
#define PP 64
#define KK 32
#define DD 384
#define DEPTH 12
#define DI 768
#define DS 16
#define DCONV 4
#define DTR 24
#define NC 40
#define LL 128  // 2*PP
#define XROW (DTR + 2 * DS)  // 56
#define NR (BB * LL)         // 1024
#define XZSPLIT 12           // split-K for xdbl mfma gemm (kchunk = 64)
#define OSPLIT 4             // split-K for out-proj gemm

using bf16x8 = __attribute__((ext_vector_type(8))) short;
using floatx4 = __attribute__((ext_vector_type(4))) float;

// ---------------------------------------------------------------- helpers
__device__ __forceinline__ float gelu_exact(float x) {
    return 0.5f * x * (1.0f + erff(x * 0.70710678118654752440f));
}
__device__ __forceinline__ float siluf(float x) {
    return x / (1.0f + expf(-x));
}
__device__ __forceinline__ unsigned short f2bf(float f) {
    unsigned u = __float_as_uint(f);
    u += 0x7fffu + ((u >> 16) & 1u);   // round-to-nearest-even
    return (unsigned short)(u >> 16);
}
__device__ __forceinline__ float bf2f(short s) {
    return __uint_as_float(((unsigned)(unsigned short)s) << 16);
}
__device__ __forceinline__ unsigned spread_bits(unsigned v) {
    v &= 1023u;
    v = (v | (v << 16)) & 50331903u;
    v = (v | (v << 8)) & 50393103u;
    v = (v | (v << 4)) & 51130563u;
    v = (v | (v << 2)) & 153391689u;
    return v;
}

// ---------------------------------------------------------------- fp32 -> bf16 bulk convert
__global__ void k_w2bf(const float* __restrict__ src, unsigned short* __restrict__ dst, int n)
{
    int i = (blockIdx.x * 256 + threadIdx.x) * 4;
    if (i >= n) return;
    float4 v = *(const float4*)(src + i);
    dst[i + 0] = f2bf(v.x);
    dst[i + 1] = f2bf(v.y);
    dst[i + 2] = f2bf(v.z);
    dst[i + 3] = f2bf(v.w);
}

// ---------------------------------------------------------------- xp -> padded bf16 (64 rows, rows 56..63 zero)
__global__ void k_xp2bf(const float* __restrict__ xp, unsigned short* __restrict__ dst)
{
    int idx = blockIdx.x * 256 + threadIdx.x;
    if (idx >= DEPTH * 64 * DI) return;
    int i = idx / (64 * DI);
    int rem = idx - i * 64 * DI;
    int n = rem / DI, k = rem % DI;
    float v = (n < XROW) ? xp[(size_t)i * XROW * DI + (size_t)n * DI + k] : 0.f;
    dst[idx] = f2bf(v);
}

// ---------------------------------------------------------------- KNN: one block per (b,p)
__global__ __launch_bounds__(256) void k_knn(const float* __restrict__ data,
                                             int* __restrict__ knn_out,
                                             float* __restrict__ centers)
{
    const int bp = blockIdx.x;
    const int b = bp >> 6, p = bp & 63;
    const int tid = threadIdx.x;
    const int lane = tid & 63, wid = tid >> 6;
    const float* X = data + (size_t)b * NN * 3;

    const float cx = X[p * 32 * 3 + 0];
    const float cy = X[p * 32 * 3 + 1];
    const float cz = X[p * 32 * 3 + 2];
    if (tid == 0) {
        centers[(b * PP + p) * 3 + 0] = cx;
        centers[(b * PP + p) * 3 + 1] = cy;
        centers[(b * PP + p) * 3 + 2] = cz;
    }

    unsigned long long pk[8];
#pragma unroll
    for (int q = 0; q < 8; q++) {
        int i = tid + 256 * q;
        float dx = cx - X[i * 3 + 0];
        float dy = cy - X[i * 3 + 1];
        float dz = cz - X[i * 3 + 2];
        float d2 = dx * dx + dy * dy + dz * dz;
        pk[q] = ((unsigned long long)__float_as_uint(d2) << 32) | (unsigned)i;
    }

    __shared__ unsigned long long wred[4];
    __shared__ int klist[KK];
    for (int k = 0; k < KK; k++) {
        unsigned long long m = pk[0];
#pragma unroll
        for (int q = 1; q < 8; q++) m = pk[q] < m ? pk[q] : m;
#pragma unroll
        for (int off = 32; off; off >>= 1) {
            unsigned long long o = __shfl_xor(m, off);
            m = o < m ? o : m;
        }
        if (lane == 0) wred[wid] = m;
        __syncthreads();
        unsigned long long g = wred[0];
#pragma unroll
        for (int w = 1; w < 4; w++) g = wred[w] < g ? wred[w] : g;
#pragma unroll
        for (int q = 0; q < 8; q++)
            if (pk[q] == g) pk[q] = ~0ull;
        if (tid == 0) klist[k] = (int)(g & 0xffffffffu);
        __syncthreads();
    }
    if (tid < KK) knn_out[bp * KK + tid] = klist[tid];
}

// ---------------------------------------------------------------- patch-embed MLP: one block per (b,p)
__global__ __launch_bounds__(256) void k_pe_mlp(
    const float* __restrict__ data, const int* __restrict__ knn_in,
    const float* __restrict__ w1, const float* __restrict__ b1,
    const float* __restrict__ g1, const float* __restrict__ be1,
    const float* __restrict__ w2, const float* __restrict__ b2,
    const float* __restrict__ g2, const float* __restrict__ be2,
    const unsigned short* __restrict__ w3bf, const float* __restrict__ b3,
    const float* __restrict__ g3, const float* __restrict__ be3,
    float* __restrict__ tokens)
{
    const int bp = blockIdx.x;
    const int b = bp >> 6, p = bp & 63;
    const int tid = threadIdx.x;
    const float* X = data + (size_t)b * NN * 3;
    const float inv_den = 0.99999500003749968752f; // 1/sqrt(1+1e-5)

    __shared__ float nxs[KK * 3];
    __shared__ float h1s[KK * 64];
    __shared__ short h2b[KK * 136];

    const float cx = X[p * 32 * 3 + 0];
    const float cy = X[p * 32 * 3 + 1];
    const float cz = X[p * 32 * 3 + 2];
    if (tid < KK) {
        int q = knn_in[bp * KK + tid];
        nxs[tid * 3 + 0] = X[q * 3 + 0] - cx;
        nxs[tid * 3 + 1] = X[q * 3 + 1] - cy;
        nxs[tid * 3 + 2] = X[q * 3 + 2] - cz;
    }
    __syncthreads();

    for (int e = tid; e < KK * 64; e += 256) {
        int j = e >> 6, c = e & 63;
        float v = nxs[j * 3 + 0] * w1[c * 3 + 0] + nxs[j * 3 + 1] * w1[c * 3 + 1] +
                  nxs[j * 3 + 2] * w1[c * 3 + 2] + b1[c];
        v = v * (g1[c] * inv_den) + be1[c];
        h1s[j * 64 + c] = gelu_exact(v);
    }
    __syncthreads();

    for (int e = tid; e < KK * 128; e += 256) {
        int j = e >> 7, c = e & 127;
        const float4* wr = (const float4*)(w2 + (size_t)c * 64);
        const float4* hr = (const float4*)(h1s + j * 64);
        float acc = 0.f;
#pragma unroll
        for (int q = 0; q < 16; q++) {
            float4 wv = wr[q], hv = hr[q];
            acc += hv.x * wv.x + hv.y * wv.y + hv.z * wv.z + hv.w * wv.w;
        }
        float v = (acc + b2[c]) * (g2[c] * inv_den) + be2[c];
        h2b[j * 136 + c] = (short)f2bf(gelu_exact(v));
    }
    __syncthreads();

    const int wave = tid >> 6, lane = tid & 63;
    const int quad = lane >> 4, r = lane & 15;
    floatx4 acc3[2][6] = {};
#pragma unroll
    for (int ks = 0; ks < 4; ks++) {
        const int k0 = ks * 32;
        bf16x8 af[2];
        af[0] = *(const bf16x8*)(h2b + (size_t)r * 136 + quad * 8 + k0);
        af[1] = *(const bf16x8*)(h2b + (size_t)(16 + r) * 136 + quad * 8 + k0);
        bf16x8 bfv[6];
#pragma unroll
        for (int nj = 0; nj < 6; nj++) {
            int n = wave * 96 + nj * 16 + r;
            bfv[nj] = *(const bf16x8*)(w3bf + (size_t)n * 128 + quad * 8 + k0);
        }
#pragma unroll
        for (int mi = 0; mi < 2; mi++)
#pragma unroll
            for (int nj = 0; nj < 6; nj++)
                acc3[mi][nj] = __builtin_amdgcn_mfma_f32_16x16x32_bf16(af[mi], bfv[nj], acc3[mi][nj], 0, 0, 0);
    }
#pragma unroll
    for (int nj = 0; nj < 6; nj++) {
        int col = wave * 96 + nj * 16 + r;
        float sc = g3[col] * inv_den;
        float offc = b3[col] * sc + be3[col];
        float m = -3.4e38f;
#pragma unroll
        for (int mi = 0; mi < 2; mi++)
#pragma unroll
            for (int r2 = 0; r2 < 4; r2++)
                m = fmaxf(m, acc3[mi][nj][r2] * sc + offc);
        m = fmaxf(m, __shfl_xor(m, 16));
        m = fmaxf(m, __shfl_xor(m, 32));
        if (quad == 0) tokens[(size_t)bp * DD + col] = m;
    }
}

// ---------------------------------------------------------------- SFC orders
__global__ __launch_bounds__(64) void k_sfc(const float* __restrict__ centers,
                                            int* __restrict__ order_h,
                                            int* __restrict__ order_th)
{
    const int b = blockIdx.x;
    const int tid = threadIdx.x;
    float cc[3];
    cc[0] = centers[(b * PP + tid) * 3 + 0];
    cc[1] = centers[(b * PP + tid) * 3 + 1];
    cc[2] = centers[(b * PP + tid) * 3 + 2];

    __shared__ float csh[PP][3];
    __shared__ float slo[3], shi[3];
    csh[tid][0] = cc[0]; csh[tid][1] = cc[1]; csh[tid][2] = cc[2];
    __syncthreads();
    if (tid == 0) {
        for (int k = 0; k < 3; k++) {
            float lo = csh[0][k], hi = csh[0][k];
            for (int j = 1; j < PP; j++) { lo = fminf(lo, csh[j][k]); hi = fmaxf(hi, csh[j][k]); }
            slo[k] = lo; shi[k] = hi;
        }
    }
    __syncthreads();

    int q[3];
    for (int k = 0; k < 3; k++) {
        float t = (cc[k] - slo[k]) / (shi[k] - slo[k] + 1e-6f) * 1023.0f;
        int qi = (int)t;
        qi = qi < 0 ? 0 : (qi > 1023 ? 1023 : qi);
        q[k] = qi;
    }
    unsigned kh = spread_bits((unsigned)q[0]) | (spread_bits((unsigned)q[1]) << 1) |
                  (spread_bits((unsigned)q[2]) << 2);
    unsigned kt = spread_bits((unsigned)q[2]) | (spread_bits((unsigned)q[1]) << 1) |
                  (spread_bits((unsigned)q[0]) << 2);

    __shared__ unsigned khs[PP], kts[PP];
    khs[tid] = kh; kts[tid] = kt;
    __syncthreads();
    int rh = 0, rt = 0;
    for (int j = 0; j < PP; j++) {
        unsigned a = khs[j];
        rh += (a < kh) || (a == kh && j < tid);
        unsigned c = kts[j];
        rt += (c < kt) || (c == kt && j < tid);
    }
    order_h[b * PP + rh] = tid;
    order_th[b * PP + rt] = tid;
}

// ---------------------------------------------------------------- build token sequence
__global__ void k_build_t(const float* __restrict__ tokens,
                          const int* __restrict__ order_h, const int* __restrict__ order_th,
                          const float* __restrict__ hs, const float* __restrict__ hb,
                          const float* __restrict__ ts, const float* __restrict__ tb,
                          const float* __restrict__ pos, float* __restrict__ t)
{
    int idx = blockIdx.x * blockDim.x + threadIdx.x;
    if (idx >= BB * LL * DD) return;
    int d = idx % DD;
    int l = (idx / DD) % LL;
    int b = idx / (DD * LL);
    float v;
    if (l < PP) {
        int src = order_h[b * PP + l];
        v = tokens[((size_t)b * PP + src) * DD + d] * hs[d] + hb[d] + pos[l * DD + d];
    } else {
        int ll2 = l - PP;
        int src = order_th[b * PP + ll2];
        v = tokens[((size_t)b * PP + src) * DD + d] * ts[d] + tb[d] + pos[ll2 * DD + d];
    }
    t[idx] = v;
}

// ---------------------------------------------------------------- residual-accumulate + LN stats + bf16 LN output
__global__ __launch_bounds__(256) void k_stats(float* __restrict__ t,
                                               const float* __restrict__ parts,
                                               const float* __restrict__ g,
                                               const float* __restrict__ gb,
                                               unsigned short* __restrict__ tbf)
{
    const int tid = threadIdx.x;
    const int wid = tid >> 6, lane = tid & 63;
    const int row = blockIdx.x * 4 + wid;
    const size_t base = (size_t)row * DD;
    float v[6];
    float s = 0.f;
#pragma unroll
    for (int j = 0; j < 6; j++) {
        int i = lane + 64 * j;
        float x = t[base + i];
        if (parts) {
            x += parts[base + i] + parts[(size_t)NR * DD + base + i] +
                 parts[2 * (size_t)NR * DD + base + i] + parts[3 * (size_t)NR * DD + base + i];
            t[base + i] = x;
        }
        v[j] = x; s += x;
    }
#pragma unroll
    for (int off = 32; off; off >>= 1) s += __shfl_xor(s, off);
    float mean = s * (1.0f / DD);
    float vs = 0.f;
#pragma unroll
    for (int j = 0; j < 6; j++) { float dd = v[j] - mean; vs += dd * dd; }
#pragma unroll
    for (int off = 32; off; off >>= 1) vs += __shfl_xor(vs, off);
    float inv = 1.0f / sqrtf(vs * (1.0f / DD) + 1e-5f);
#pragma unroll
    for (int j = 0; j < 6; j++) {
        int i = lane + 64 * j;
        tbf[base + i] = f2bf((v[j] - mean) * inv * g[i] + gb[i]);
    }
}

// ---------------------------------------------------------------- xz MFMA GEMM + fused conv/SiLU epilogue
// grid (12, 8): y-block = one batch (128 tokens).  Cols n0<768 -> xc channels:
// C tile -> LDS (bf16) -> causal conv + SiLU -> xcbf.  Cols >=768 -> z: SiLU -> zsbf.
__global__ __launch_bounds__(256) void k_mfma_xz(
    const unsigned short* __restrict__ tbf,
    const unsigned short* __restrict__ inwbf,
    const float* __restrict__ cw, const float* __restrict__ cb,
    unsigned short* __restrict__ xcbf, unsigned short* __restrict__ zsbf)
{
    __shared__ short ct[128][136];
    const int tid = threadIdx.x;
    const int wave = tid >> 6, lane = tid & 63;
    const int quad = lane >> 4, r = lane & 15;
    const int wm = wave >> 1, wn = wave & 1;
    const int b = blockIdx.y;
    const int n0 = blockIdx.x * 128;
    const int m0 = b * 128 + wm * 64;

    floatx4 acc[4][4] = {};
    const unsigned short* Ab = tbf + (size_t)(m0 + r) * DD + quad * 8;
    const unsigned short* Bb = inwbf + (size_t)(n0 + wn * 64 + r) * DD + quad * 8;
    for (int k0 = 0; k0 < DD; k0 += 32) {
        bf16x8 af[4], bfv[4];
#pragma unroll
        for (int i = 0; i < 4; i++) {
            af[i] = *(const bf16x8*)(Ab + (size_t)(i * 16) * DD + k0);
            bfv[i] = *(const bf16x8*)(Bb + (size_t)(i * 16) * DD + k0);
        }
#pragma unroll
        for (int i = 0; i < 4; i++)
#pragma unroll
            for (int j = 0; j < 4; j++)
                acc[i][j] = __builtin_amdgcn_mfma_f32_16x16x32_bf16(af[i], bfv[j], acc[i][j], 0, 0, 0);
    }

    // C -> LDS (bf16).  row = wm*64 + i*16 + quad*4 + r2, col = wn*64 + j*16 + r
#pragma unroll
    for (int i = 0; i < 4; i++)
#pragma unroll
        for (int r2 = 0; r2 < 4; r2++) {
            short* cp = &ct[wm * 64 + i * 16 + quad * 4 + r2][wn * 64 + r];
#pragma unroll
            for (int j = 0; j < 4; j++)
                cp[j * 16] = (short)f2bf(acc[i][j][r2]);
        }
    __syncthreads();

    const int l0 = (tid >> 4) * 8;
    const int c0 = (tid & 15) * 8;
    if (n0 < DI) {
        // xc path: causal conv over rows + SiLU
        float cwv[8][4], cbv[8];
#pragma unroll
        for (int q = 0; q < 8; q++) {
            *(float4*)cwv[q] = *(const float4*)(cw + (size_t)(n0 + c0 + q) * 4);
            cbv[q] = cb[n0 + c0 + q];
        }
#pragma unroll
        for (int dl = 0; dl < 8; dl++) {
            const int l = l0 + dl;
            float u[8];
#pragma unroll
            for (int q = 0; q < 8; q++) u[q] = cbv[q];
#pragma unroll
            for (int j = 0; j < DCONV; j++) {
                int lt = l - (DCONV - 1) + j;
                if (lt >= 0) {
                    bf16x8 x = *(const bf16x8*)&ct[lt][c0];
#pragma unroll
                    for (int q = 0; q < 8; q++) u[q] += bf2f(x[q]) * cwv[q][j];
                }
            }
            unsigned short o[8];
#pragma unroll
            for (int q = 0; q < 8; q++) o[q] = f2bf(siluf(u[q]));
            *(bf16x8*)(xcbf + (size_t)(b * LL + l) * DI + n0 + c0) = *(bf16x8*)o;
        }
    } else {
        const int nz = n0 - DI;
#pragma unroll
        for (int dl = 0; dl < 8; dl++) {
            const int l = l0 + dl;
            bf16x8 x = *(const bf16x8*)&ct[l][c0];
            unsigned short o[8];
#pragma unroll
            for (int q = 0; q < 8; q++) o[q] = f2bf(siluf(bf2f(x[q])));
            *(bf16x8*)(zsbf + (size_t)(b * LL + l) * DI + nz + c0) = *(bf16x8*)o;
        }
    }
}

// ---------------------------------------------------------------- xdbl MFMA GEMM (plain bf16, A = xcbf)
// parts[z][NR][XROW] = xcbf[:, z*64 .. +63] @ xpbf^T.  grid (1, 4, XZSPLIT).
__global__ __launch_bounds__(256) void k_mfma_xdbl(
    const unsigned short* __restrict__ xcbf,
    const unsigned short* __restrict__ xpbf,
    float* __restrict__ parts)
{
    const int tid = threadIdx.x;
    const int wave = tid >> 6, lane = tid & 63;
    const int quad = lane >> 4, r = lane & 15;
    const int rowbase = blockIdx.y * 256 + wave * 64;
    const int z = blockIdx.z;
    const int kbeg = z * (DI / XZSPLIT);   // 64

    floatx4 acc[4][4] = {};
#pragma unroll
    for (int k0 = 0; k0 < DI / XZSPLIT; k0 += 32) {
        bf16x8 af[4], bfv[4];
#pragma unroll
        for (int i = 0; i < 4; i++) {
            af[i] = *(const bf16x8*)(xcbf + (size_t)(rowbase + i * 16 + r) * DI + kbeg + k0 + quad * 8);
            bfv[i] = *(const bf16x8*)(xpbf + (size_t)(i * 16 + r) * DI + kbeg + k0 + quad * 8);
        }
#pragma unroll
        for (int mi = 0; mi < 4; mi++)
#pragma unroll
            for (int nj = 0; nj < 4; nj++)
                acc[mi][nj] = __builtin_amdgcn_mfma_f32_16x16x32_bf16(af[mi], bfv[nj], acc[mi][nj], 0, 0, 0);
    }

    float* out = parts + (size_t)z * NR * XROW;
#pragma unroll
    for (int mi = 0; mi < 4; mi++)
#pragma unroll
        for (int nj = 0; nj < 4; nj++) {
            int col = nj * 16 + r;
            if (col < XROW) {
#pragma unroll
                for (int r2 = 0; r2 < 4; r2++) {
                    int row = rowbase + mi * 16 + quad * 4 + r2;
                    out[(size_t)row * XROW + col] = acc[mi][nj][r2];
                }
            }
        }
}

// ---------------------------------------------------------------- reduce xdbl partials
__global__ void k_xred(const float* __restrict__ parts, float* __restrict__ xdbl)
{
    int i = blockIdx.x * 256 + threadIdx.x;
    if (i >= NR * XROW) return;
    float s = 0.f;
#pragma unroll
    for (int z = 0; z < XZSPLIT; z++) s += parts[(size_t)z * NR * XROW + i];
    xdbl[i] = s;
}

// ---------------------------------------------------------------- chunk-parallel selective scan (bf16 u/z in, bf16 y out)
__global__ __launch_bounds__(256) void k_scan(
    const float* __restrict__ xdbl,
    const unsigned short* __restrict__ xcbf, const unsigned short* __restrict__ zsbf,
    const float* __restrict__ dtw, const float* __restrict__ dtb,
    const float* __restrict__ Alog, const float* __restrict__ Dp,
    unsigned short* __restrict__ ybf)
{
    const int tid = threadIdx.x;
    const int b = blockIdx.x / (DI / 2);
    const int d0 = (blockIdx.x % (DI / 2)) * 2;

    __shared__ float da[LL][33];
    __shared__ float Bsh[LL][DS];
    __shared__ float Csh[LL][DS];
    __shared__ float dus[LL][2];
    __shared__ float us[LL][2];
    __shared__ float zs[LL][2];
    __shared__ float ApL[2][DS][9];
    __shared__ float HlL[2][DS][9];
    __shared__ float hst[2][DS][9];

    {
        const int t = tid >> 1, dl = tid & 1;
        const int d = d0 + dl;
        const size_t row = (size_t)b * LL + t;
        const float* xd = xdbl + row * XROW;
        const float* w = dtw + d * DTR;
        float acc = dtb[d];
#pragma unroll
        for (int k = 0; k < DTR; k++) acc += xd[k] * w[k];
        float delta = fmaxf(acc, 0.f) + log1pf(__expf(-fabsf(acc)));  // softplus
        float u = bf2f((short)xcbf[row * DI + d]);
        dus[t][dl] = delta * u;
        us[t][dl] = u;
        zs[t][dl] = bf2f((short)zsbf[row * DI + d]);
#pragma unroll
        for (int s = 0; s < DS; s++)
            da[t][2 * s + dl] = __expf(delta * (-__expf(Alog[d * DS + s])));
    }
    for (int i = tid; i < LL * DS; i += 256) {
        int t = i >> 4, s = i & 15;
        const float* xd = xdbl + ((size_t)b * LL + t) * XROW;
        Bsh[t][s] = xd[DTR + s];
        Csh[t][s] = xd[DTR + DS + s];
    }
    __syncthreads();

    const int s = tid & 15;
    const int dl = (tid >> 4) & 1;
    const int c = tid >> 5;

    {
        float h = 0.f, Ap = 1.f;
#pragma unroll
        for (int q = 0; q < 16; q++) {
            int t = c * 16 + q;
            float a = da[t][2 * s + dl];
            h = h * a + dus[t][dl] * Bsh[t][s];
            Ap *= a;
        }
        ApL[dl][s][c] = Ap;
        HlL[dl][s][c] = h;
    }
    __syncthreads();
    if (tid < 32) {
        int s2 = tid & 15, d2 = tid >> 4;
        float hs = 0.f;
#pragma unroll
        for (int cc = 0; cc < 8; cc++) {
            hst[d2][s2][cc] = hs;
            hs = ApL[d2][s2][cc] * hs + HlL[d2][s2][cc];
        }
    }
    __syncthreads();

    {
        const float Dd = Dp[d0 + dl];
        float h = hst[dl][s][c];
        unsigned short* yc = ybf + ((size_t)b * LL + c * 16) * DI + (d0 + dl);
#pragma unroll
        for (int q = 0; q < 16; q++) {
            int t = c * 16 + q;
            float a = da[t][2 * s + dl];
            h = h * a + dus[t][dl] * Bsh[t][s];
            float p = h * Csh[t][s];
            p += __shfl_xor(p, 1, 16);
            p += __shfl_xor(p, 2, 16);
            p += __shfl_xor(p, 4, 16);
            p += __shfl_xor(p, 8, 16);
            if (s == 0) yc[(size_t)q * DI] = f2bf((p + Dd * us[t][dl]) * zs[t][dl]);
        }
    }
}

// ---------------------------------------------------------------- bf16 MFMA GEMM, 128x128 tile (out-proj)
__global__ __launch_bounds__(256) void k_mfma_gemm(
    const unsigned short* __restrict__ Abf, int lda,
    const unsigned short* __restrict__ Wbf, int ldb,
    float* __restrict__ C, int ldc, size_t cstride, int kchunk)
{
    const int tid = threadIdx.x;
    const int wave = tid >> 6, lane = tid & 63;
    const int quad = lane >> 4, r = lane & 15;
    const int wm = wave >> 1, wn = wave & 1;
    const int m0 = blockIdx.y * 128 + wm * 64;
    const int n0 = blockIdx.x * 128 + wn * 64;
    const int kbeg = blockIdx.z * kchunk;
    float* Cz = C + (size_t)blockIdx.z * cstride;

    floatx4 acc[4][4] = {};

    const unsigned short* Ab = Abf + (size_t)(m0 + r) * lda + quad * 8 + kbeg;
    const unsigned short* Bb = Wbf + (size_t)(n0 + r) * ldb + quad * 8 + kbeg;

    for (int k0 = 0; k0 < kchunk; k0 += 32) {
        bf16x8 af[4], bf[4];
#pragma unroll
        for (int i = 0; i < 4; i++) {
            af[i] = *(const bf16x8*)(Ab + (size_t)(i * 16) * lda + k0);
            bf[i] = *(const bf16x8*)(Bb + (size_t)(i * 16) * ldb + k0);
        }
#pragma unroll
        for (int i = 0; i < 4; i++)
#pragma unroll
            for (int j = 0; j < 4; j++)
                acc[i][j] = __builtin_amdgcn_mfma_f32_16x16x32_bf16(af[i], bf[j], acc[i][j], 0, 0, 0);
    }

#pragma unroll
    for (int i = 0; i < 4; i++)
#pragma unroll
        for (int r2 = 0; r2 < 4; r2++) {
            float* cp = Cz + (size_t)(m0 + i * 16 + quad * 4 + r2) * ldc + n0 + r;
#pragma unroll
            for (int j = 0; j < 4; j++)
                cp[j * 16] = acc[i][j][r2];
        }
}

// ---------------------------------------------------------------- final layernorm (wave per row) + residual partials
__global__ __launch_bounds__(64) void k_ln(const float* __restrict__ x,
                                           const float* __restrict__ parts,
                                           const float* __restrict__ g,
                                           const float* __restrict__ bb,
                                           float* __restrict__ y)
{
    const int row = blockIdx.x;
    const int tid = threadIdx.x;
    const size_t base = (size_t)row * DD;
    float v[6];
    float s = 0.f;
#pragma unroll
    for (int j = 0; j < 6; j++) {
        int i = tid + 64 * j;
        float xv = x[base + i] + parts[base + i] + parts[(size_t)NR * DD + base + i] +
                   parts[2 * (size_t)NR * DD + base + i] + parts[3 * (size_t)NR * DD + base + i];
        v[j] = xv; s += xv;
    }
#pragma unroll
    for (int off = 32; off; off >>= 1) s += __shfl_xor(s, off);
    float mean = s * (1.0f / DD);
    float vs = 0.f;
#pragma unroll
    for (int j = 0; j < 6; j++) { float dd = v[j] - mean; vs += dd * dd; }
#pragma unroll
    for (int off = 32; off; off >>= 1) vs += __shfl_xor(vs, off);
    float inv = 1.0f / sqrtf(vs * (1.0f / DD) + 1e-5f);
#pragma unroll
    for (int j = 0; j < 6; j++) {
        int i = tid + 64 * j;
        y[base + i] = (v[j] - mean) * inv * g[i] + bb[i];
    }
}

// ---------------------------------------------------------------- mean over L
__global__ void k_mean(const float* __restrict__ xln, float* __restrict__ pooled)
{
    int idx = blockIdx.x * blockDim.x + threadIdx.x;
    if (idx >= BB * DD) return;
    int b = idx / DD, d = idx % DD;
    float sv = 0.f;
    for (int l = 0; l < LL; l++) sv += xln[((size_t)b * LL + l) * DD + d];
    pooled[idx] = sv / (float)LL;
}

// ---------------------------------------------------------------- head MLP (one block per batch)
__global__ __launch_bounds__(256) void k_mlp(const float* __restrict__ pooled,
    const float* __restrict__ w1, const float* __restrict__ b1,
    const float* __restrict__ w2, const float* __restrict__ b2,
    const float* __restrict__ w3, const float* __restrict__ b3,
    float* __restrict__ out)
{
    int b = blockIdx.x, tid = threadIdx.x;
    __shared__ float pl[DD];
    __shared__ float h1[256];
    __shared__ float h2[64];
    for (int i = tid; i < DD; i += 256) pl[i] = pooled[b * DD + i];
    __syncthreads();
    {
        float acc = b1[tid];
        const float* wr = w1 + (size_t)tid * DD;
        for (int k = 0; k < DD; k++) acc += pl[k] * wr[k];
        h1[tid] = fmaxf(acc, 0.f);
    }
    __syncthreads();
    if (tid < 64) {
        float acc = b2[tid];
        const float* wr = w2 + (size_t)tid * 256;
        for (int k = 0; k < 256; k++) acc += h1[k] * wr[k];
        h2[tid] = fmaxf(acc, 0.f);
    }
    __syncthreads();
    if (tid < NC) {
        float acc = b3[tid];
        const float* wr = w3 + (size_t)tid * 64;
        for (int k = 0; k < 64; k++) acc += h2[k] * wr[k];
        out[b * NC + tid] = acc;
    }
}

// ---------------------------------------------------------------- launch
extern "C" void kernel_launch(void* const* d_in, const int* in_sizes, int n_in,
                              void* d_out, int out_size, void* d_ws, size_t ws_size,
                              hipStream_t stream)
{
    const float* data      = (const float*)d_in[0];
    const float* pe_w1     = (const float*)d_in[1];
    const float* pe_b1     = (const float*)d_in[2];
    const float* pe_g1     = (const float*)d_in[3];
    const float* pe_be1    = (const float*)d_in[4];
    const float* pe_w2     = (const float*)d_in[5];
    const float* pe_b2     = (const float*)d_in[6];
    const float* pe_g2     = (const float*)d_in[7];
    const float* pe_be2    = (const float*)d_in[8];
    const float* pe_w3     = (const float*)d_in[9];
    const float* pe_b3     = (const float*)d_in[10];
    const float* pe_g3     = (const float*)d_in[11];
    const float* pe_be3    = (const float*)d_in[12];
    const float* oi_h_scale  = (const float*)d_in[13];
    const float* oi_h_shift  = (const float*)d_in[14];
    const float* oi_th_scale = (const float*)d_in[15];
    const float* oi_th_shift = (const float*)d_in[16];
    const float* pos_embed = (const float*)d_in[17];
    const float* blk_ln_g  = (const float*)d_in[18];
    const float* blk_ln_b  = (const float*)d_in[19];
    const float* blk_in_w  = (const float*)d_in[20];
    const float* blk_conv_w = (const float*)d_in[21];
    const float* blk_conv_b = (const float*)d_in[22];
    const float* blk_xp_w  = (const float*)d_in[23];
    const float* blk_dt_w  = (const float*)d_in[24];
    const float* blk_dt_b  = (const float*)d_in[25];
    const float* blk_Alog  = (const float*)d_in[26];
    const float* blk_D     = (const float*)d_in[27];
    const float* blk_out_w = (const float*)d_in[28];
    const float* norm_g    = (const float*)d_in[29];
    const float* norm_b    = (const float*)d_in[30];
    const float* mlp_w1    = (const float*)d_in[31];
    const float* mlp_b1    = (const float*)d_in[32];
    const float* mlp_w2    = (const float*)d_in[33];
    const float* mlp_b2    = (const float*)d_in[34];
    const float* mlp_w3    = (const float*)d_in[35];
    const float* mlp_b3    = (const float*)d_in[36];

    float* ws = (float*)d_ws;
    size_t off = 0;
    auto alloc = [&](size_t n) { float* p = ws + off; off += (n + 63) & ~(size_t)63; return p; };
    float* tokens  = alloc((size_t)BB * PP * DD);
    float* centers = alloc((size_t)BB * PP * 3);
    int*   order_h = (int*)alloc((size_t)BB * PP);
    int*   order_th= (int*)alloc((size_t)BB * PP);
    int*   knn_idx = (int*)alloc((size_t)BB * PP * KK);
    float* t    = alloc((size_t)NR * DD);
    float* xln  = alloc((size_t)NR * DD);
    float* xdbl = alloc((size_t)NR * XROW);
    float* pooled = alloc((size_t)BB * DD);
    float* parts_out = alloc((size_t)OSPLIT * NR * DD);
    float* parts_x   = alloc((size_t)XZSPLIT * NR * XROW);
    unsigned short* tbf   = (unsigned short*)alloc((size_t)NR * DD / 2);
    unsigned short* xcbf  = (unsigned short*)alloc((size_t)NR * DI / 2);
    unsigned short* zsbf  = (unsigned short*)alloc((size_t)NR * DI / 2);
    unsigned short* ybf   = (unsigned short*)alloc((size_t)NR * DI / 2);
    unsigned short* inwbf = (unsigned short*)alloc((size_t)DEPTH * 2 * DI * DD / 2);
    unsigned short* owbf  = (unsigned short*)alloc((size_t)DEPTH * DD * DI / 2);
    unsigned short* xpbf  = (unsigned short*)alloc((size_t)DEPTH * 64 * DI / 2);
    unsigned short* w3bf  = (unsigned short*)alloc((size_t)DD * 128 / 2);

    // one-shot weight conversion to bf16
    {
        int n1 = DEPTH * 2 * DI * DD;
        int n2 = DEPTH * DD * DI;
        int n3 = DD * 128;
        int n4 = DEPTH * 64 * DI;
        k_w2bf<<<(n1 / 4 + 255) / 256, 256, 0, stream>>>(blk_in_w, inwbf, n1);
        k_w2bf<<<(n2 / 4 + 255) / 256, 256, 0, stream>>>(blk_out_w, owbf, n2);
        k_w2bf<<<(n3 / 4 + 255) / 256, 256, 0, stream>>>(pe_w3, w3bf, n3);
        k_xp2bf<<<(n4 + 255) / 256, 256, 0, stream>>>(blk_xp_w, xpbf);
    }

    k_knn<<<BB * PP, 256, 0, stream>>>(data, knn_idx, centers);
    k_pe_mlp<<<BB * PP, 256, 0, stream>>>(data, knn_idx,
        pe_w1, pe_b1, pe_g1, pe_be1, pe_w2, pe_b2, pe_g2, pe_be2,
        w3bf, pe_b3, pe_g3, pe_be3, tokens);
    k_sfc<<<BB, 64, 0, stream>>>(centers, order_h, order_th);
    {
        int nt = BB * LL * DD;
        k_build_t<<<(nt + 255) / 256, 256, 0, stream>>>(tokens, order_h, order_th,
            oi_h_scale, oi_h_shift, oi_th_scale, oi_th_shift, pos_embed, t);
    }

    for (int i = 0; i < DEPTH; i++) {
        const float* ln_g = blk_ln_g + i * DD;
        const float* ln_b = blk_ln_b + i * DD;
        const float* cw   = blk_conv_w + (size_t)i * DI * DCONV;
        const float* cb   = blk_conv_b + (size_t)i * DI;
        const float* dtw  = blk_dt_w + (size_t)i * DI * DTR;
        const float* dtb  = blk_dt_b + (size_t)i * DI;
        const float* Al   = blk_Alog + (size_t)i * DI * DS;
        const float* Dpp  = blk_D + (size_t)i * DI;
        const unsigned short* inw = inwbf + (size_t)i * 2 * DI * DD;
        const unsigned short* ow  = owbf + (size_t)i * DD * DI;
        const unsigned short* xpb = xpbf + (size_t)i * 64 * DI;

        k_stats<<<NR / 4, 256, 0, stream>>>(t, (i == 0) ? nullptr : parts_out, ln_g, ln_b, tbf);
        k_mfma_xz<<<dim3(12, BB), 256, 0, stream>>>(tbf, inw, cw, cb, xcbf, zsbf);
        k_mfma_xdbl<<<dim3(1, NR / 256, XZSPLIT), 256, 0, stream>>>(xcbf, xpb, parts_x);
        k_xred<<<(NR * XROW + 255) / 256, 256, 0, stream>>>(parts_x, xdbl);
        k_scan<<<BB * DI / 2, 256, 0, stream>>>(xdbl, xcbf, zsbf, dtw, dtb, Al, Dpp, ybf);
        k_mfma_gemm<<<dim3(DD / 128, NR / 128, OSPLIT), 256, 0, stream>>>(
            ybf, DI, ow, DI, parts_out, DD, (size_t)NR * DD, DI / OSPLIT);
    }

    k_ln<<<NR, 64, 0, stream>>>(t, parts_out, norm_g, norm_b, xln);
    k_mean<<<(BB * DD + 255) / 256, 256, 0, stream>>>(xln, pooled);
    k_mlp<<<BB, 256, 0, stream>>>(pooled, mlp_w1, mlp_b1, mlp_w2, mlp_b2, mlp_w3, mlp_b3,
                                  (float*)d_out);
}